// Round 5
// baseline (775.896 us; speedup 1.0000x reference)
//
#include <hip/hip_runtime.h>
#include <stdint.h>

#define Q 4096
#define N 65536
#define D 128
#define TOPK 21
#define CAP 128
// Phi^-1(1 - 64/4096) : expected 64 candidates per column
#define ZTH 2.1539f
#define SCALE 8192.0f
// prune margin: 0.9 score units in packed (score*8192)<<12 representation
#define MARGIN_W (((uint64_t)7372) << 12)

typedef short bf16x8 __attribute__((ext_vector_type(8)));
typedef float floatx4 __attribute__((ext_vector_type(4)));

__device__ inline ushort f2bf(float f) {
    uint32_t u = __float_as_uint(f);
    uint32_t r = (u + 0x7FFFu + ((u >> 16) & 1u)) >> 16;
    return (ushort)r;
}

// ---------------- Kernel 0: convert fp32->bf16, compute per-column threshold ----
__global__ __launch_bounds__(256)
void k_convert(const float* __restrict__ xq, const float* __restrict__ xb,
               ushort* __restrict__ xqb, ushort* __restrict__ xbb,
               float* __restrict__ thr) {
    int wave = threadIdx.x >> 6;
    int lane = threadIdx.x & 63;
    int b = blockIdx.x;
    if (b < Q / 4) {
        int row = b * 4 + wave;
        float2 v = ((const float2*)(xq + (size_t)row * D))[lane];
        ushort2 u;
        u.x = f2bf(v.x);
        u.y = f2bf(v.y);
        ((ushort2*)(xqb + (size_t)row * D))[lane] = u;
    } else {
        int row = (b - Q / 4) * 4 + wave;
        float2 v = ((const float2*)(xb + (size_t)row * D))[lane];
        ushort2 u;
        u.x = f2bf(v.x);
        u.y = f2bf(v.y);
        ((ushort2*)(xbb + (size_t)row * D))[lane] = u;
        float nrm = v.x * v.x + v.y * v.y;
        #pragma unroll
        for (int off = 32; off; off >>= 1) nrm += __shfl_xor(nrm, off, 64);
        if (lane == 0) thr[row] = ZTH * sqrtf(nrm);
    }
}

// ---------------- Kernel 1: barrier-free register-resident GEMM -----------------
// 1024 blocks, one per 64-column tile. 4 waves/block, each owns 1024 queries.
// B frags + thresholds register-resident; A frags loaded straight from L2/L3 to
// registers (full 256B rows, coalesced 16 rows x 64B per instr). NO LDS staging,
// NO barriers in the K loop -> compiler software-pipelines loads under MFMAs.
// Epilogue packs candidates as (score*8192)<<12 | q  (20-bit score, 12-bit q).
__global__ __launch_bounds__(256, 2)
void k_score(const ushort* __restrict__ xqb, const ushort* __restrict__ xbb,
             const float* __restrict__ thr, int* __restrict__ cnt,
             uint32_t* __restrict__ cand) {
    __shared__ int cnt_lds[64];
    const int t = threadIdx.x;
    const int tile = blockIdx.x;          // 0..1023
    const int wv = t >> 6, ln = t & 63;
    const int lr = ln & 15, quad = ln >> 4;

    if (t < 64) cnt_lds[t] = 0;

    // resident B fragments + thresholds (loaded once)
    bf16x8 bfr[4][4];   // [kk][j]
    float tc[4];
    #pragma unroll
    for (int j = 0; j < 4; j++) {
        int n = tile * 64 + j * 16 + lr;
        tc[j] = thr[n];
        #pragma unroll
        for (int kk = 0; kk < 4; kk++)
            bfr[kk][j] = *(const bf16x8*)&xbb[(size_t)n * D + kk * 32 + quad * 8];
    }
    __syncthreads();   // cnt_lds init visible

    const int qwbase = wv * 1024;
    for (int it = 0; it < 16; it++) {
        const int qb = qwbase + it * 64;

        bf16x8 a[4][4];    // [kk][i] -- full 256B row per (i,lr), 16B/lane
        #pragma unroll
        for (int i = 0; i < 4; i++) {
            const ushort* rowp = xqb + (size_t)(qb + i * 16 + lr) * D;
            #pragma unroll
            for (int kk = 0; kk < 4; kk++)
                a[kk][i] = *(const bf16x8*)(rowp + kk * 32 + quad * 8);
        }

        floatx4 acc[4][4];
        #pragma unroll
        for (int i = 0; i < 4; i++)
            #pragma unroll
            for (int j = 0; j < 4; j++)
                acc[i][j] = (floatx4){0.f, 0.f, 0.f, 0.f};

        #pragma unroll
        for (int kk = 0; kk < 4; kk++)
            #pragma unroll
            for (int i = 0; i < 4; i++)
                #pragma unroll
                for (int j = 0; j < 4; j++)
                    acc[i][j] = __builtin_amdgcn_mfma_f32_16x16x32_bf16(
                        a[kk][i], bfr[kk][j], acc[i][j], 0, 0, 0);

        // epilogue: C/D layout col=lane&15 (-> n), row=quad*4+reg (-> q)
        #pragma unroll
        for (int j = 0; j < 4; j++) {
            int nl = j * 16 + lr;
            int n  = tile * 64 + nl;
            #pragma unroll
            for (int i = 0; i < 4; i++) {
                int qg = qb + i * 16 + quad * 4;
                #pragma unroll
                for (int r = 0; r < 4; r++) {
                    float s = acc[i][j][r];
                    if (s > tc[j]) {
                        int pos = atomicAdd(&cnt_lds[nl], 1);
                        if (pos < CAP) {
                            uint32_t fix = (uint32_t)fminf(s * SCALE, 1048575.0f);
                            cand[(size_t)n * CAP + pos] = (fix << 12) | (uint32_t)(qg + r);
                        }
                    }
                }
            }
        }
    }
    __syncthreads();
    if (t < 64) cnt[tile * 64 + t] = cnt_lds[t];
}

// ---------------- Kernel 2: prune by packed bf16 score, stage survivors to LDS
// coalesced, exact fp32 sequential-FMA rescore (bit-matches BLAS sgemm chain),
// rank via register shuffles, emit top-21. ------------------------------------
__global__ __launch_bounds__(128, 4)
void k_select(const float* __restrict__ xq, const float* __restrict__ xb,
              const int* __restrict__ cnt, const uint32_t* __restrict__ cand,
              int* __restrict__ out) {
    __shared__ __align__(16) float rows[64 * 132];  // 64 rows, stride 132 floats
    __shared__ float xbs[128];
    __shared__ uint32_t sw[128];
    __shared__ int sq[64];
    __shared__ int smisc[4];   // [0]=tau, [1]=wave0 keep count, [2]=total kept
    const int n = blockIdx.x, t = threadIdx.x;
    const int wv = t >> 6, ln = t & 63;

    xbs[t] = xb[(size_t)n * D + t];
    int c = cnt[n]; if (c > CAP) c = CAP;
    uint32_t w = 0;
    if (t < c) w = cand[(size_t)n * CAP + t];
    sw[t] = w;
    if (t < 4) smisc[t] = 0;
    __syncthreads();

    // rank by packed word among all c (words are unique: low 12 bits = q)
    int r = 0;
    #pragma unroll
    for (int j = 0; j < 64; j++) {
        uint32_t wj = (uint32_t)__shfl((int)w, j);
        r += (wj > w) ? 1 : 0;
    }
    if (c > 64) {            // cross-wave compares only when needed (~half of cols)
        const int ob = (wv ^ 1) * 64;
        for (int j = 0; j < 64; j++) r += (sw[ob + j] > w) ? 1 : 0;
    }
    if (t < c && r == 20) smisc[0] = (int)w;   // tau = 21st-largest (c>=21 whp)
    __syncthreads();
    const uint64_t tau = (uint64_t)(uint32_t)smisc[0];

    // keep set: s~ >= tau - 0.9  (64-bit math: no overflow corner)
    bool keep = (t < c) && ((uint64_t)w + MARGIN_W >= tau);
    unsigned long long mk = __ballot(keep);
    if (wv == 0 && ln == 0) smisc[1] = (int)__popcll(mk);
    __syncthreads();
    int base = (wv == 0) ? 0 : smisc[1];
    int pos = base + (int)__popcll(mk & ((1ull << ln) - 1ull));
    if (keep && pos < 64) sq[pos] = (int)(w & 0xFFFu);
    if (ln == 0) atomicAdd(&smisc[2], (int)__popcll(mk));
    __syncthreads();
    int m = smisc[2]; if (m > 64) m = 64;

    // stage survivor rows, coalesced (32 lanes x float4 = contiguous 512B/row),
    // chunk rotated by 2*row -> conflict-free b128 writes AND chain reads
    {
        int row0 = t >> 5;        // 4 rows per round
        int chunk = t & 31;
        for (int rr = row0; rr < m; rr += 4) {
            int q = sq[rr];
            float4 v = ((const float4*)xq)[(size_t)q * 32 + chunk];
            int p = (chunk + 2 * rr) & 31;
            *(float4*)&rows[rr * 132 + p * 4] = v;
        }
    }
    __syncthreads();

    // exact fp32 chain: single accumulator, ascending k (BLAS sgemm order)
    float a0 = -INFINITY;
    int myq = 0x7fffffff;
    if (t < m) {
        myq = sq[t];
        float acc = 0.0f;
        #pragma unroll
        for (int ch = 0; ch < 32; ch++) {
            int p = (ch + 2 * t) & 31;
            float4 v = *(const float4*)&rows[t * 132 + p * 4];
            acc = fmaf(v.x, xbs[4 * ch + 0], acc);
            acc = fmaf(v.y, xbs[4 * ch + 1], acc);
            acc = fmaf(v.z, xbs[4 * ch + 2], acc);
            acc = fmaf(v.w, xbs[4 * ch + 3], acc);
        }
        a0 = acc;
    }

    // final rank among survivors (m <= 64 -> wave 0 only), shuffle-based
    if (wv == 0) {
        int rr = 0;
        #pragma unroll
        for (int j = 0; j < 64; j++) {
            float sj = __shfl(a0, j);
            int qj = __shfl(myq, j);
            rr += ((sj > a0) || (sj == a0 && qj < myq)) ? 1 : 0;
        }
        if (ln < m && rr < TOPK) out[(size_t)rr * N + n] = myq;
    }
    // statistically-never fallback: fill unfilled ranks if fewer than 21 kept
    if (m < TOPK && t >= m && t < TOPK) out[(size_t)t * N + n] = 0;
}

extern "C" void kernel_launch(void* const* d_in, const int* in_sizes, int n_in,
                              void* d_out, int out_size, void* d_ws, size_t ws_size,
                              hipStream_t stream) {
    const float* xq = (const float*)d_in[0];
    const float* xb = (const float*)d_in[1];
    int* out = (int*)d_out;

    char* ws = (char*)d_ws;
    ushort*   xqb = (ushort*)ws;                     //  1,048,576 B
    ushort*   xbb = (ushort*)(ws + 1048576);         // 16,777,216 B
    float*    thr = (float*)(ws + 17825792);         //    262,144 B
    int*      cnt = (int*)(ws + 18087936);           //    262,144 B
    uint32_t* cand = (uint32_t*)(ws + 18350080);     // 33,554,432 B  (total ~51.9 MB)

    k_convert<<<Q / 4 + N / 4, 256, 0, stream>>>(xq, xb, xqb, xbb, thr);
    k_score<<<N / 64, 256, 0, stream>>>(xqb, xbb, thr, cnt, cand);
    k_select<<<N, 128, 0, stream>>>(xq, xb, cnt, cand, out);
}

// Round 6
// 394.707 us; speedup vs baseline: 1.9658x; 1.9658x over previous
//
#include <hip/hip_runtime.h>
#include <stdint.h>

#define Q 4096
#define N 65536
#define D 128
#define TOPK 21
#define CAP 128
// Phi^-1(1 - 64/4096) : expected 64 candidates per column
#define ZTH 2.1539f
#define SCALE 8192.0f
// prune margin: 0.35 score units (~15 sigma of bf16 score error) in fix units
#define MARGIN_S 2867
#define RWS 12   // rescore rows per round

typedef short bf16x8 __attribute__((ext_vector_type(8)));
typedef float floatx4 __attribute__((ext_vector_type(4)));

__device__ inline ushort f2bf(float f) {
    uint32_t u = __float_as_uint(f);
    uint32_t r = (u + 0x7FFFu + ((u >> 16) & 1u)) >> 16;
    return (ushort)r;
}

// within-wave LDS handoff: complete outstanding LDS ops, block compiler reordering
__device__ inline void wave_lds_fence() {
    asm volatile("s_waitcnt lgkmcnt(0)" ::: "memory");
}

// ---------------- Kernel 0: convert fp32->bf16, compute per-column threshold ----
__global__ __launch_bounds__(256)
void k_convert(const float* __restrict__ xq, const float* __restrict__ xb,
               ushort* __restrict__ xqb, ushort* __restrict__ xbb,
               float* __restrict__ thr) {
    int wave = threadIdx.x >> 6;
    int lane = threadIdx.x & 63;
    int b = blockIdx.x;
    if (b < Q / 4) {
        int row = b * 4 + wave;
        float2 v = ((const float2*)(xq + (size_t)row * D))[lane];
        ushort2 u;
        u.x = f2bf(v.x);
        u.y = f2bf(v.y);
        ((ushort2*)(xqb + (size_t)row * D))[lane] = u;
    } else {
        int row = (b - Q / 4) * 4 + wave;
        float2 v = ((const float2*)(xb + (size_t)row * D))[lane];
        ushort2 u;
        u.x = f2bf(v.x);
        u.y = f2bf(v.y);
        ((ushort2*)(xbb + (size_t)row * D))[lane] = u;
        float nrm = v.x * v.x + v.y * v.y;
        #pragma unroll
        for (int off = 32; off; off >>= 1) nrm += __shfl_xor(nrm, off, 64);
        if (lane == 0) thr[row] = ZTH * sqrtf(nrm);
    }
}

// ---------------- Kernel 1: R4-proven streaming GEMM (B-in-regs, A via LDS) -----
// 512 blocks, one per 128-column group. Epilogue packs (score*8192)<<12 | q.
__global__ __launch_bounds__(256, 2)
void k_score(const ushort* __restrict__ xqb, const ushort* __restrict__ xbb,
             const float* __restrict__ thr, int* __restrict__ cnt,
             uint32_t* __restrict__ cand) {
    __shared__ ushort As[128 * 128];   // 32KB: 128 rows x 256B
    __shared__ int cnt_lds[128];

    const int t = threadIdx.x;
    const int bn = blockIdx.x;             // 0..511
    const int wave = t >> 6, lane = t & 63;
    const int wq = wave & 1, wc = wave >> 1;
    const int lr = lane & 15, quad = lane >> 4;

    if (t < 128) cnt_lds[t] = 0;

    // resident B fragments + thresholds (loaded once)
    bf16x8 bfr[4][4];
    float tc[4];
    #pragma unroll
    for (int j = 0; j < 4; j++) {
        int n = bn * 128 + wc * 64 + j * 16 + lr;
        tc[j] = thr[n];
        #pragma unroll
        for (int kk = 0; kk < 4; kk++)
            bfr[kk][j] = *(const bf16x8*)&xbb[(size_t)n * D + kk * 32 + quad * 8];
    }
    __syncthreads();   // cnt_lds init visible

    for (int it = 0; it < Q / 128; it++) {
        __syncthreads();   // all waves done reading previous tile
        const ushort* tile = xqb + (size_t)it * 128 * D;
        #pragma unroll
        for (int i = 0; i < 8; i++) {
            int c = wave * 8 + i;                 // 1KB chunk id (0..31)
            int r = c * 4 + (lane >> 4);          // row within tile
            int p = (lane & 15) ^ (r & 15);       // swizzled 16B chunk in row
            const ushort* gp = tile + r * D + p * 8;
            __builtin_amdgcn_global_load_lds(
                (const __attribute__((address_space(1))) uint32_t*)(uintptr_t)gp,
                (__attribute__((address_space(3))) uint32_t*)(uintptr_t)(As + c * 512),
                16, 0, 0);
        }
        __syncthreads();   // staging complete

        floatx4 acc[4][4];
        #pragma unroll
        for (int i = 0; i < 4; i++)
            #pragma unroll
            for (int j = 0; j < 4; j++)
                acc[i][j] = (floatx4){0.f, 0.f, 0.f, 0.f};

        #pragma unroll
        for (int kk = 0; kk < 4; kk++) {
            bf16x8 a[4];
            #pragma unroll
            for (int i = 0; i < 4; i++) {
                int q = wq * 64 + i * 16 + lr;
                int p = (kk * 4 + quad) ^ lr;     // un-swizzle
                a[i] = *(const bf16x8*)&As[q * D + p * 8];
            }
            #pragma unroll
            for (int i = 0; i < 4; i++)
                #pragma unroll
                for (int j = 0; j < 4; j++)
                    acc[i][j] = __builtin_amdgcn_mfma_f32_16x16x32_bf16(
                        a[i], bfr[kk][j], acc[i][j], 0, 0, 0);
        }

        // epilogue: C/D layout col=lane&15 (-> n), row=quad*4+reg (-> q)
        #pragma unroll
        for (int j = 0; j < 4; j++) {
            int nl = wc * 64 + j * 16 + lr;
            int n  = bn * 128 + nl;
            #pragma unroll
            for (int i = 0; i < 4; i++) {
                int qg = it * 128 + wq * 64 + i * 16 + quad * 4;
                #pragma unroll
                for (int r = 0; r < 4; r++) {
                    float s = acc[i][j][r];
                    if (s > tc[j]) {
                        int pos = atomicAdd(&cnt_lds[nl], 1);
                        if (pos < CAP) {
                            uint32_t fix = (uint32_t)fminf(s * SCALE, 1048575.0f);
                            cand[(size_t)n * CAP + pos] = (fix << 12) | (uint32_t)(qg + r);
                        }
                    }
                }
            }
        }
    }
    __syncthreads();
    if (t < 128) cnt[bn * 128 + t] = cnt_lds[t];
}

// ---------------- Kernel 2: wave-autonomous prune + exact rescore ---------------
// One wave per column; 4 waves/block; ZERO __syncthreads (per-wave LDS + fences).
// tau = 21st-largest packed score via 20-step ballot binary search; keep within
// 0.35 (~15 sigma) of tau (~24 rows). Stage kept rows coalesced to a 12-row LDS
// buffer per round; exact BLAS-order fp32 fmaf chain; rank via LDS broadcast.
__global__ __launch_bounds__(256, 4)
void k_select(const float* __restrict__ xq, const float* __restrict__ xb,
              const int* __restrict__ cnt, const uint32_t* __restrict__ cand,
              int* __restrict__ out) {
    __shared__ float bufS[4][RWS * 132];
    __shared__ float xbsS[4][128];
    __shared__ int   sqS[4][64];
    __shared__ float scS[4][64];

    const int t = threadIdx.x;
    const int wv = t >> 6, ln = t & 63;
    const int n = blockIdx.x * 4 + wv;

    float* bufL = bufS[wv];
    float* xbsL = xbsS[wv];
    int*   sqL  = sqS[wv];
    float* scL  = scS[wv];

    // stage this column's xb row (wave-private)
    {
        float2 v = ((const float2*)(xb + (size_t)n * D))[ln];
        xbsL[ln * 2]     = v.x;
        xbsL[ln * 2 + 1] = v.y;
    }

    int c = cnt[n]; if (c > CAP) c = CAP;
    uint32_t w0 = 0, w1 = 0;
    if (ln < c)      w0 = cand[(size_t)n * CAP + ln];
    if (ln + 64 < c) w1 = cand[(size_t)n * CAP + 64 + ln];
    const uint32_t s0 = w0 >> 12, s1 = w1 >> 12;

    // tau = 21st-largest packed score (20-bit) via ballot binary search
    uint32_t lo = 0;
    #pragma unroll
    for (int b = 19; b >= 0; b--) {
        uint32_t mid = lo | (1u << b);
        int cc = (int)__popcll(__ballot(s0 >= mid)) + (int)__popcll(__ballot(s1 >= mid));
        if (cc >= TOPK) lo = mid;
    }

    // keep set: s >= tau - margin; compact into sqL via ballots
    bool k0 = (ln < c)      && (s0 + MARGIN_S >= lo);
    bool k1 = (ln + 64 < c) && (s1 + MARGIN_S >= lo);
    unsigned long long m0 = __ballot(k0), m1 = __ballot(k1);
    int n0 = (int)__popcll(m0);
    int m = n0 + (int)__popcll(m1); if (m > 64) m = 64;
    unsigned long long ltm = (ln == 63) ? ~0ull >> 1 : ((1ull << ln) - 1ull);
    // note: (1ull<<63)-1 is fine too; guard anyway
    ltm = (1ull << ln) - 1ull;
    if (k0) { int p = (int)__popcll(m0 & ltm);      if (p < 64) sqL[p] = (int)(w0 & 0xFFFu); }
    if (k1) { int p = n0 + (int)__popcll(m1 & ltm); if (p < 64) sqL[p] = (int)(w1 & 0xFFFu); }
    wave_lds_fence();   // sqL + xbsL visible to all lanes of this wave

    // rescore in rounds of RWS rows
    for (int base = 0; base < m; base += RWS) {
        int rows = m - base; if (rows > RWS) rows = RWS;
        // coalesced stage: 32 lanes x float4 = contiguous 512B per row, 2 rows/instr
        int r2 = ln >> 5;          // 0..1
        int ch = ln & 31;          // 16B chunk
        #pragma unroll
        for (int i = 0; i < RWS / 2; i++) {
            int rr = i * 2 + r2;
            if (rr < rows) {
                int q = sqL[base + rr];
                float4 v = ((const float4*)xq)[(size_t)q * 32 + ch];
                *(float4*)&bufL[rr * 132 + ch * 4] = v;
            }
        }
        wave_lds_fence();   // buffer staged (vmcnt handled by data dep on v)
        if (ln < rows) {
            float acc = 0.0f;
            #pragma unroll
            for (int cc = 0; cc < 32; cc++) {
                float4 v = *(const float4*)&bufL[ln * 132 + cc * 4];
                acc = fmaf(v.x, xbsL[4 * cc + 0], acc);
                acc = fmaf(v.y, xbsL[4 * cc + 1], acc);
                acc = fmaf(v.z, xbsL[4 * cc + 2], acc);
                acc = fmaf(v.w, xbsL[4 * cc + 3], acc);
            }
            scL[base + ln] = acc;
        }
        wave_lds_fence();   // scores written; buffer reusable next round
    }

    // final exact rank among m survivors (LDS broadcast reads)
    float s = (ln < m) ? scL[ln] : -INFINITY;
    int myq = (ln < m) ? sqL[ln] : 0x7fffffff;
    int r = 0;
    for (int j = 0; j < m; j++) {
        float sj = scL[j];
        int   qj = sqL[j];
        r += ((sj > s) || (sj == s && qj < myq)) ? 1 : 0;
    }
    if (ln < m && r < TOPK) out[(size_t)r * N + n] = myq;
    // statistically-never fallback: fill unfilled ranks if fewer than 21 kept
    if (m < TOPK && ln >= m && ln < TOPK) out[(size_t)ln * N + n] = 0;
}

extern "C" void kernel_launch(void* const* d_in, const int* in_sizes, int n_in,
                              void* d_out, int out_size, void* d_ws, size_t ws_size,
                              hipStream_t stream) {
    const float* xq = (const float*)d_in[0];
    const float* xb = (const float*)d_in[1];
    int* out = (int*)d_out;

    char* ws = (char*)d_ws;
    ushort*   xqb = (ushort*)ws;                     //  1,048,576 B
    ushort*   xbb = (ushort*)(ws + 1048576);         // 16,777,216 B
    float*    thr = (float*)(ws + 17825792);         //    262,144 B
    int*      cnt = (int*)(ws + 18087936);           //    262,144 B
    uint32_t* cand = (uint32_t*)(ws + 18350080);     // 33,554,432 B  (total ~51.9 MB)

    k_convert<<<Q / 4 + N / 4, 256, 0, stream>>>(xq, xb, xqb, xbb, thr);
    k_score<<<N / 128, 256, 0, stream>>>(xqb, xbb, thr, cnt, cand);
    k_select<<<N / 4, 256, 0, stream>>>(xq, xb, cnt, cand, out);
}